// Round 3
// baseline (251.569 us; speedup 1.0000x reference)
//
#include <hip/hip_runtime.h>

#define NPTS  50000
#define NEDGE 800000
#define ICH   16
#define OCH   16
#define HID   64
#define NTILES 50000   // NEDGE/16

typedef short bf16x8 __attribute__((ext_vector_type(8)));
typedef float f32x4  __attribute__((ext_vector_type(4)));

// tanh-form GELU: gelu(v) = v * (1 - 1/(1+exp(2*0.7978845608*(v + 0.044715 v^3))))
// |err vs exact erf gelu| <= ~3e-4, ~8 VALU ops.
__device__ __forceinline__ float gelu_tanh(float v) {
    float v2 = v * v;
    float u2 = v * fmaf(v2, 0.0713548162726f, 1.5957691216057f); // 2*sqrt(2/pi)*(1 + 0.044715 v^2)
    float e  = __expf(u2);
    float r  = __builtin_amdgcn_rcpf(e + 1.0f);
    return v - v * r;
}

// fp32 -> bf16 round-to-nearest-even
__device__ __forceinline__ short f2bf(float f) {
    unsigned u = __builtin_bit_cast(unsigned, f);
    unsigned r = (u + 0x7FFFu + ((u >> 16) & 1u)) >> 16;
    return (short)r;
}

__global__ void zero_out_kernel(float* __restrict__ out, int n) {
    int i = blockIdx.x * blockDim.x + threadIdx.x;
    if (i < n) out[i] = 0.0f;
}

// Transposed-operand scheme: all GEMMs computed as H^T = W(A-operand) @ H^T(B-operand).
// Weight fragments staged in LDS in exact MFMA A-fragment order:
//   frag[slot][lane] is a bf16x8; read = ds_read_b128 at base+lane*16+slot*1024 (imm).
// Block = 512 threads (8 waves); each wave processes 4 tiles of 16 edges.
__global__ __launch_bounds__(512, 4) void edge_mfma_kernel(
    const float* __restrict__ x,    // [NPTS*16]
    const float* __restrict__ pos,  // [NPTS*3]
    const int*   __restrict__ ei,   // [2*NEDGE]
    const float* __restrict__ W1,   // [6*64]
    const float* __restrict__ b1,   // [64]
    const float* __restrict__ Wh,   // [64*64]
    const float* __restrict__ bh,   // [64]
    const float* __restrict__ Wo,   // [64*256]
    const float* __restrict__ bo,   // [256]
    float* __restrict__ out)        // [NPTS*16]
{
    // A-fragment-ordered weight stores. Slot = one 16x16x32 MFMA A operand.
    __shared__ bf16x8 WoF[32][64];  // slot = i*2+kt  (i=0..15 output-ch tiles, kt k-tile)   32 KB
    __shared__ bf16x8 WhF[8][64];   // slot = m*2+kt  (m=0..3 hidden n-tiles)                 8 KB
    __shared__ bf16x8 W1F[4][64];   // slot = m       (K zero-padded 6->32; k==6 holds b1)    4 KB
    __shared__ bf16x8 BOF[64];      // bo as A-frag: BOt[o=er][i=grp*8+j], i<16               1 KB

    const int tid = threadIdx.x;

    // ---------------- stage weight fragments (once per block) ----------------
    // WoF: 2048 lane-entries, 4 per thread.
#pragma unroll
    for (int p = 0; p < 4; ++p) {
        int e_id = p * 512 + tid;            // 0..2047
        int s  = e_id >> 6;                  // slot 0..31
        int l  = e_id & 63;
        int er = l & 15, g = l >> 4;
        int i  = s >> 1, kt = s & 1;
        int n  = i * 16 + er;
        int kb = kt * 32 + g * 8;
        bf16x8 f;
#pragma unroll
        for (int j = 0; j < 8; ++j)
            f[j] = f2bf(Wo[(kb + j) * 256 + n]);
        WoF[s][l] = f;
    }
    // WhF: 512 entries, 1 per thread.
    {
        int s  = tid >> 6;                   // 0..7
        int l  = tid & 63;
        int er = l & 15, g = l >> 4;
        int m  = s >> 1, kt = s & 1;
        int n  = m * 16 + er;
        int kb = kt * 32 + g * 8;
        bf16x8 f;
#pragma unroll
        for (int j = 0; j < 8; ++j)
            f[j] = f2bf(Wh[(kb + j) * 64 + n]);
        WhF[s][l] = f;
    }
    // W1F: 256 entries (k<6 = W1, k==6 = b1 [bias rides the zero-pad slot], else 0).
    if (tid < 256) {
        int m  = tid >> 6;
        int l  = tid & 63;
        int er = l & 15, g = l >> 4;
        int n  = m * 16 + er;
        bf16x8 f;
#pragma unroll
        for (int j = 0; j < 8; ++j) {
            int k = g * 8 + j;
            float v = (k < 6) ? W1[k * 64 + n] : (k == 6 ? b1[n] : 0.0f);
            f[j] = f2bf(v);
        }
        W1F[m][l] = f;
    }
    // BOF: 64 entries.
    if (tid < 64) {
        int er = tid & 15, g = tid >> 4;
        bf16x8 f;
#pragma unroll
        for (int j = 0; j < 8; ++j) {
            int i = g * 8 + j;
            f[j] = (g < 2) ? f2bf(bo[i * 16 + er]) : (short)0;
        }
        BOF[tid] = f;
    }
    __syncthreads();

    const int wave = tid >> 6;
    const int lane = tid & 63;
    const int grp  = lane >> 4;   // 0..3
    const int er   = lane & 15;

    // per-lane bh values: bhv[m][r] = bh[m*16 + grp*4 + r]
    float bhv[4][4];
#pragma unroll
    for (int m = 0; m < 4; ++m)
#pragma unroll
        for (int r = 0; r < 4; ++r)
            bhv[m][r] = bh[m * 16 + grp * 4 + r];

    // bpermute source-lane addresses (bytes): src = er + (2*(grp&1)+h)*16
    const int addrH0 = (er + (grp & 1) * 32) * 4;
    const int addrH1 = addrH0 + 64;
    const bool selHi = (grp >= 2);

    const bf16x8* wof = &WoF[0][lane];
    const bf16x8* whf = &WhF[0][lane];
    const bf16x8* w1f = &W1F[0][lane];
    const bf16x8  bofr = BOF[lane];
    const f32x4 zero = {0.f, 0.f, 0.f, 0.f};

#pragma unroll 1
    for (int t = 0; t < 4; ++t) {
        const int gt = blockIdx.x * 32 + wave * 4 + t;
        if (gt >= NTILES) break;
        const int ebase = gt << 4;

        // ---- per-edge loads: lane's edge = er (4-way redundant across grp) ----
        int s = ei[ebase + er];
        int d = ei[NEDGE + ebase + er];
        s = min(max(s, 0), NPTS - 1);
        d = min(max(d, 0), NPTS - 1);

        float p0 = pos[s * 3 + 0], p1 = pos[s * 3 + 1], p2 = pos[s * 3 + 2];
        float p3 = pos[d * 3 + 0], p4 = pos[d * 3 + 1], p5 = pos[d * 3 + 2];

        float xr[16];
        {
            const float4* xp = reinterpret_cast<const float4*>(x + (size_t)s * 16);
            float4 a = xp[0], b = xp[1], c = xp[2], dd = xp[3];
            xr[0]=a.x; xr[1]=a.y; xr[2]=a.z; xr[3]=a.w;
            xr[4]=b.x; xr[5]=b.y; xr[6]=b.z; xr[7]=b.w;
            xr[8]=c.x; xr[9]=c.y; xr[10]=c.z; xr[11]=c.w;
            xr[12]=dd.x; xr[13]=dd.y; xr[14]=dd.z; xr[15]=dd.w;
        }

        // ---- B1 frag: PE^T[k][e=er]; only grp0 lanes nonzero; k==6 is the bias 1.0 ----
        bf16x8 ape;
        ape[0] = (grp == 0) ? f2bf(p0) : (short)0;
        ape[1] = (grp == 0) ? f2bf(p1) : (short)0;
        ape[2] = (grp == 0) ? f2bf(p2) : (short)0;
        ape[3] = (grp == 0) ? f2bf(p3) : (short)0;
        ape[4] = (grp == 0) ? f2bf(p4) : (short)0;
        ape[5] = (grp == 0) ? f2bf(p5) : (short)0;
        ape[6] = (grp == 0) ? (short)0x3F80 : (short)0;   // bf16(1.0) -> picks up b1
        ape[7] = 0;

        // ---- layer 1: H1^T[n][e], 4 m-tiles; bias folded; gelu ----
        float g1[4][4];
#pragma unroll
        for (int m = 0; m < 4; ++m) {
            f32x4 c = __builtin_amdgcn_mfma_f32_16x16x32_bf16(w1f[m * 64], ape, zero, 0, 0, 0);
#pragma unroll
            for (int r = 0; r < 4; ++r) g1[m][r] = gelu_tanh(c[r]);
        }

        // ---- build B2 frags (H1^T as B operand) via in-wave bpermute ----
        // dest lane (er,grp), elem j=h*4+r, k=kt*32+grp*8+j:
        //   src lane = er + (2*(grp&1)+h)*16 ; src reg = g1[2kt + (grp>>1)][r]
        bf16x8 B2[2];
#pragma unroll
        for (int kt = 0; kt < 2; ++kt) {
#pragma unroll
            for (int h = 0; h < 2; ++h) {
                int ah = h ? addrH1 : addrH0;
#pragma unroll
                for (int r = 0; r < 4; ++r) {
                    int vA = __builtin_amdgcn_ds_bpermute(ah, __builtin_bit_cast(int, g1[2 * kt][r]));
                    int vB = __builtin_amdgcn_ds_bpermute(ah, __builtin_bit_cast(int, g1[2 * kt + 1][r]));
                    float v = __builtin_bit_cast(float, selHi ? vB : vA);
                    B2[kt][h * 4 + r] = f2bf(v);
                }
            }
        }

        // ---- layer 2: H2^T = WhA @ H1^T, + bh, gelu ----
        float g2[4][4];
#pragma unroll
        for (int m = 0; m < 4; ++m) {
            f32x4 c = __builtin_amdgcn_mfma_f32_16x16x32_bf16(whf[(m * 2 + 0) * 64], B2[0], zero, 0, 0, 0);
            c = __builtin_amdgcn_mfma_f32_16x16x32_bf16(whf[(m * 2 + 1) * 64], B2[1], c, 0, 0, 0);
#pragma unroll
            for (int r = 0; r < 4; ++r) g2[m][r] = gelu_tanh(c[r] + bhv[m][r]);
        }

        // ---- build B3 frags from g2 (same shuffle pattern) ----
        bf16x8 B3[2];
#pragma unroll
        for (int kt = 0; kt < 2; ++kt) {
#pragma unroll
            for (int h = 0; h < 2; ++h) {
                int ah = h ? addrH1 : addrH0;
#pragma unroll
                for (int r = 0; r < 4; ++r) {
                    int vA = __builtin_amdgcn_ds_bpermute(ah, __builtin_bit_cast(int, g2[2 * kt][r]));
                    int vB = __builtin_amdgcn_ds_bpermute(ah, __builtin_bit_cast(int, g2[2 * kt + 1][r]));
                    float v = __builtin_bit_cast(float, selHi ? vB : vA);
                    B3[kt][h * 4 + r] = f2bf(v);
                }
            }
        }

        // ---- bo contribution: msg = BOt @ X^T  (one MFMA, K zero-padded 16->32) ----
        // xb frag: B[k=i][e=er] = x[er-edge][i], i = grp*8+j -> grp<2 lanes only.
        bf16x8 xb;
#pragma unroll
        for (int j = 0; j < 8; ++j) {
            float v = (grp == 0) ? xr[j] : ((grp == 1) ? xr[j + 8] : 0.0f);
            xb[j] = (grp < 2) ? f2bf(v) : (short)0;
        }
        f32x4 msg = __builtin_amdgcn_mfma_f32_16x16x32_bf16(bofr, xb, zero, 0, 0, 0);

        // ---- layer 3 + einsum: per i-tile, C rows n = i*16 + grp*4 + r -> o = grp*4+r ----
        // msg[r] += x[e=er][i] * C_i[r]
#pragma unroll
        for (int i = 0; i < 16; ++i) {
            f32x4 c = __builtin_amdgcn_mfma_f32_16x16x32_bf16(wof[(2 * i + 0) * 64], B3[0], zero, 0, 0, 0);
            c = __builtin_amdgcn_mfma_f32_16x16x32_bf16(wof[(2 * i + 1) * 64], B3[1], c, 0, 0, 0);
#pragma unroll
            for (int r = 0; r < 4; ++r)
                msg[r] = fmaf(xr[i], c[r], msg[r]);
        }

        // ---- scatter: lane owns (edge er, channels grp*4+r) -> coalesced atomics ----
        float* op = out + (size_t)d * 16 + grp * 4;
#pragma unroll
        for (int r = 0; r < 4; ++r)
            atomicAdd(op + r, msg[r]);
    }
}

extern "C" void kernel_launch(void* const* d_in, const int* in_sizes, int n_in,
                              void* d_out, int out_size, void* d_ws, size_t ws_size,
                              hipStream_t stream) {
    const float* x   = (const float*)d_in[0];
    const float* pos = (const float*)d_in[1];
    const int*   ei  = (const int*)d_in[2];
    const float* W1  = (const float*)d_in[3];
    const float* b1  = (const float*)d_in[4];
    const float* Wh  = (const float*)d_in[5];
    const float* bh  = (const float*)d_in[6];
    const float* Wo  = (const float*)d_in[7];
    const float* bo  = (const float*)d_in[8];
    float* out = (float*)d_out;

    zero_out_kernel<<<(out_size + 255) / 256, 256, 0, stream>>>(out, out_size);
    const int nblocks = (NTILES + 31) / 32;   // 32 tiles per 512-thread block
    edge_mfma_kernel<<<nblocks, 512, 0, stream>>>(
        x, pos, ei, W1, b1, Wh, bh, Wo, bo, out);
}

// Round 4
// 215.219 us; speedup vs baseline: 1.1689x; 1.1689x over previous
//
#include <hip/hip_runtime.h>

#define NPTS   50000
#define NEDGE  800000
#define NTILES 50000   // NEDGE/16

typedef short bf16x8 __attribute__((ext_vector_type(8)));
typedef float f32x4  __attribute__((ext_vector_type(4)));

// tanh-form GELU, |err| <= ~3e-4 vs exact erf gelu (threshold is 0.171; measured absmax 0.03)
__device__ __forceinline__ float gelu_tanh(float v) {
    float v2 = v * v;
    float u2 = v * fmaf(v2, 0.0713548162726f, 1.5957691216057f);
    float e  = __expf(u2);
    float r  = __builtin_amdgcn_rcpf(e + 1.0f);
    return v - v * r;
}

// fp32 -> bf16 round-to-nearest-even
__device__ __forceinline__ short f2bf(float f) {
    unsigned u = __builtin_bit_cast(unsigned, f);
    unsigned r = (u + 0x7FFFu + ((u >> 16) & 1u)) >> 16;
    return (short)r;
}

__device__ __forceinline__ int bperm(int addr, int v) {
    return __builtin_amdgcn_ds_bpermute(addr, v);
}
__device__ __forceinline__ int fbits(float v) { return __builtin_bit_cast(int, v); }
__device__ __forceinline__ float ibits(int v) { return __builtin_bit_cast(float, v); }

__global__ void zero_out_kernel(float* __restrict__ out, int n) {
    int i = blockIdx.x * blockDim.x + threadIdx.x;
    if (i < n) out[i] = 0.0f;
}

// Transposed-operand MFMA scheme + 2-tile software pipeline.
// Block = 512 threads (8 waves); each wave: 4 tiles of 16 edges, as 2 pipelined pairs.
__global__ __launch_bounds__(512, 4) void edge_mfma_kernel(
    const float* __restrict__ x,    // [NPTS*16]
    const float* __restrict__ pos,  // [NPTS*3]
    const int*   __restrict__ ei,   // [2*NEDGE]
    const float* __restrict__ W1,   // [6*64]
    const float* __restrict__ b1,   // [64]
    const float* __restrict__ Wh,   // [64*64]
    const float* __restrict__ bh,   // [64]
    const float* __restrict__ Wo,   // [64*256]
    const float* __restrict__ bo,   // [256]
    float* __restrict__ out)        // [NPTS*16]
{
    // A-fragment-ordered weight stores: frag[slot][lane] = bf16x8, read at base+lane*16+imm.
    __shared__ bf16x8 WoF[32][64];  // 32 KB : slot = i*2+kt
    __shared__ bf16x8 WhF[8][64];   //  8 KB : slot = m*2+kt
    __shared__ bf16x8 W1F[4][64];   //  4 KB : slot = m (K zero-pad 6->32; k==6 holds b1)
    __shared__ bf16x8 BOF[64];      //  1 KB : bo as A-frag
    __shared__ float  bhs[64];      // 256 B

    const int tid = threadIdx.x;

    // ---------------- stage weight fragments (once per block) ----------------
#pragma unroll
    for (int p = 0; p < 4; ++p) {
        int e_id = p * 512 + tid;            // 0..2047
        int s  = e_id >> 6;                  // slot 0..31
        int l  = e_id & 63;
        int er_ = l & 15, g = l >> 4;
        int i  = s >> 1, kt = s & 1;
        int n  = i * 16 + er_;
        int kb = kt * 32 + g * 8;
        bf16x8 f;
#pragma unroll
        for (int j = 0; j < 8; ++j)
            f[j] = f2bf(Wo[(kb + j) * 256 + n]);
        WoF[s][l] = f;
    }
    {
        int s  = tid >> 6;                   // 0..7
        int l  = tid & 63;
        int er_ = l & 15, g = l >> 4;
        int m  = s >> 1, kt = s & 1;
        int n  = m * 16 + er_;
        int kb = kt * 32 + g * 8;
        bf16x8 f;
#pragma unroll
        for (int j = 0; j < 8; ++j)
            f[j] = f2bf(Wh[(kb + j) * 64 + n]);
        WhF[s][l] = f;
    }
    if (tid < 256) {
        int m  = tid >> 6;
        int l  = tid & 63;
        int er_ = l & 15, g = l >> 4;
        int n  = m * 16 + er_;
        bf16x8 f;
#pragma unroll
        for (int j = 0; j < 8; ++j) {
            int k = g * 8 + j;
            float v = (k < 6) ? W1[k * 64 + n] : (k == 6 ? b1[n] : 0.0f);
            f[j] = f2bf(v);
        }
        W1F[m][l] = f;
    }
    if (tid < 64) {
        int er_ = tid & 15, g = tid >> 4;
        bf16x8 f;
#pragma unroll
        for (int j = 0; j < 8; ++j) {
            int i = g * 8 + j;
            f[j] = (g < 2) ? f2bf(bo[i * 16 + er_]) : (short)0;
        }
        BOF[tid] = f;
        bhs[tid] = bh[tid];
    }
    __syncthreads();

    const int wave = tid >> 6;
    const int lane = tid & 63;
    const int grp  = lane >> 4;   // 0..3
    const int er   = lane & 15;

    // bpermute addresses (bytes), all loop-invariant
    const int addrH0 = (er + (grp & 1) * 32) * 4;    // B-frag build, h=0
    const int addrH1 = addrH0 + 64;                  // h=1
    const bool selHi = (grp >= 2);
    int addrT[4], addrD[4];                          // msg transpose / dst gather
#pragma unroll
    for (int r = 0; r < 4; ++r) {
        addrT[r] = ((er >> 2) * 16 + grp * 4 + r) * 4;
        addrD[r] = (grp * 4 + r) * 4;
    }
    const int selT = er & 3;

    const bf16x8* wof = &WoF[0][lane];
    const bf16x8* whf = &WhF[0][lane];
    const bf16x8* w1f = &W1F[0][lane];
    const bf16x8  bofr = BOF[lane];
    const f32x4 zero = {0.f, 0.f, 0.f, 0.f};

    const int tbase = blockIdx.x * 32 + wave * 4;

    // ---- prologue: hoist ei/pos loads + ape-frag build for all 4 tiles ----
    bf16x8 apeT[4];
    int sT[4], dT[4];
#pragma unroll
    for (int tt = 0; tt < 4; ++tt) {
        int gt = tbase + tt; if (gt >= NTILES) gt = NTILES - 1;  // clamp loads; atomics guarded below
        int eb = gt << 4;
        int s = ei[eb + er];
        int d = ei[NEDGE + eb + er];
        s = min(max(s, 0), NPTS - 1);
        d = min(max(d, 0), NPTS - 1);
        sT[tt] = s; dT[tt] = d;
        float p0 = pos[s * 3 + 0], p1 = pos[s * 3 + 1], p2 = pos[s * 3 + 2];
        float p3 = pos[d * 3 + 0], p4 = pos[d * 3 + 1], p5 = pos[d * 3 + 2];
        const bool g0 = (grp == 0);
        bf16x8 ap;
        ap[0] = g0 ? f2bf(p0) : (short)0;
        ap[1] = g0 ? f2bf(p1) : (short)0;
        ap[2] = g0 ? f2bf(p2) : (short)0;
        ap[3] = g0 ? f2bf(p3) : (short)0;
        ap[4] = g0 ? f2bf(p4) : (short)0;
        ap[5] = g0 ? f2bf(p5) : (short)0;
        ap[6] = g0 ? (short)0x3F80 : (short)0;   // bf16(1.0) picks up b1 (k==6 slot)
        ap[7] = 0;
        apeT[tt] = ap;
    }

    // ---- main: 2 pairs, each pair = 2 tiles pipelined stage-by-stage ----
#pragma unroll
    for (int pp = 0; pp < 2; ++pp) {
        const int t0 = 2 * pp;

        // x[src] loads for both tiles (issued early; consumed at einsum)
        float xr[2][16];
#pragma unroll
        for (int q = 0; q < 2; ++q) {
            const float4* xp = reinterpret_cast<const float4*>(x + (size_t)sT[t0 + q] * 16);
            float4 a = xp[0], b = xp[1], c = xp[2], dd = xp[3];
            xr[q][0]=a.x;  xr[q][1]=a.y;  xr[q][2]=a.z;  xr[q][3]=a.w;
            xr[q][4]=b.x;  xr[q][5]=b.y;  xr[q][6]=b.z;  xr[q][7]=b.w;
            xr[q][8]=c.x;  xr[q][9]=c.y;  xr[q][10]=c.z; xr[q][11]=c.w;
            xr[q][12]=dd.x; xr[q][13]=dd.y; xr[q][14]=dd.z; xr[q][15]=dd.w;
        }

        // ---- layer 1: H1^T = W1F @ PE^T, gelu (bias folded into K) ----
        float g1[2][4][4];
#pragma unroll
        for (int q = 0; q < 2; ++q)
#pragma unroll
            for (int m = 0; m < 4; ++m) {
                f32x4 c = __builtin_amdgcn_mfma_f32_16x16x32_bf16(w1f[m * 64], apeT[t0 + q], zero, 0, 0, 0);
#pragma unroll
                for (int r = 0; r < 4; ++r) g1[q][m][r] = gelu_tanh(c[r]);
            }

        // ---- build B2 frags via in-wave bpermute ----
        bf16x8 B2[2][2];
#pragma unroll
        for (int q = 0; q < 2; ++q)
#pragma unroll
            for (int kt = 0; kt < 2; ++kt)
#pragma unroll
                for (int h = 0; h < 2; ++h) {
                    int ah = h ? addrH1 : addrH0;
#pragma unroll
                    for (int r = 0; r < 4; ++r) {
                        int vA = bperm(ah, fbits(g1[q][2 * kt][r]));
                        int vB = bperm(ah, fbits(g1[q][2 * kt + 1][r]));
                        B2[q][kt][h * 4 + r] = f2bf(ibits(selHi ? vB : vA));
                    }
                }

        // ---- layer 2: H2^T = WhF @ H1^T + bh, gelu ----
        float g2[2][4][4];
#pragma unroll
        for (int q = 0; q < 2; ++q)
#pragma unroll
            for (int m = 0; m < 4; ++m) {
                f32x4 c = __builtin_amdgcn_mfma_f32_16x16x32_bf16(whf[(2 * m + 0) * 64], B2[q][0], zero, 0, 0, 0);
                c = __builtin_amdgcn_mfma_f32_16x16x32_bf16(whf[(2 * m + 1) * 64], B2[q][1], c, 0, 0, 0);
                float4 b4 = *reinterpret_cast<const float4*>(&bhs[m * 16 + grp * 4]);
                float bb[4] = {b4.x, b4.y, b4.z, b4.w};
#pragma unroll
                for (int r = 0; r < 4; ++r) g2[q][m][r] = gelu_tanh(c[r] + bb[r]);
            }

        // ---- build B3 frags ----
        bf16x8 B3[2][2];
#pragma unroll
        for (int q = 0; q < 2; ++q)
#pragma unroll
            for (int kt = 0; kt < 2; ++kt)
#pragma unroll
                for (int h = 0; h < 2; ++h) {
                    int ah = h ? addrH1 : addrH0;
#pragma unroll
                    for (int r = 0; r < 4; ++r) {
                        int vA = bperm(ah, fbits(g2[q][2 * kt][r]));
                        int vB = bperm(ah, fbits(g2[q][2 * kt + 1][r]));
                        B3[q][kt][h * 4 + r] = f2bf(ibits(selHi ? vB : vA));
                    }
                }

        // ---- bo contribution: msg = BOF @ X^T (K zero-padded 16->32) ----
        f32x4 msg[2];
#pragma unroll
        for (int q = 0; q < 2; ++q) {
            bf16x8 xb;
#pragma unroll
            for (int j = 0; j < 8; ++j) {
                float v = (grp == 0) ? xr[q][j] : ((grp == 1) ? xr[q][j + 8] : 0.0f);
                xb[j] = (grp < 2) ? f2bf(v) : (short)0;
            }
            msg[q] = __builtin_amdgcn_mfma_f32_16x16x32_bf16(bofr, xb, zero, 0, 0, 0);
        }

        // ---- layer 3 + einsum, q-interleaved for MFMA ILP ----
#pragma unroll
        for (int i = 0; i < 16; ++i)
#pragma unroll
            for (int q = 0; q < 2; ++q) {
                f32x4 c = __builtin_amdgcn_mfma_f32_16x16x32_bf16(wof[(2 * i + 0) * 64], B3[q][0], zero, 0, 0, 0);
                c = __builtin_amdgcn_mfma_f32_16x16x32_bf16(wof[(2 * i + 1) * 64], B3[q][1], c, 0, 0, 0);
#pragma unroll
                for (int r = 0; r < 4; ++r)
                    msg[q][r] = fmaf(xr[q][i], c[r], msg[q][r]);
            }

        // ---- transpose msg across lanes -> line-packed atomics (64B/edge) ----
        // src: lane(grp,er) reg r = M[e=er][o=grp*4+r]
        // dst: lane(grp,er) reg rd = M[e=grp*4+rd][o=er]  (write: one instr = 16 contiguous ch/edge)
#pragma unroll
        for (int q = 0; q < 2; ++q) {
            const int gt = tbase + t0 + q;
            const bool ok = (gt < NTILES);
#pragma unroll
            for (int rd = 0; rd < 4; ++rd) {
                int u0 = bperm(addrT[rd], fbits(msg[q][0]));
                int u1 = bperm(addrT[rd], fbits(msg[q][1]));
                int u2 = bperm(addrT[rd], fbits(msg[q][2]));
                int u3 = bperm(addrT[rd], fbits(msg[q][3]));
                int v  = (selT == 0) ? u0 : (selT == 1) ? u1 : (selT == 2) ? u2 : u3;
                int dv = bperm(addrD[rd], dT[t0 + q]);
                if (ok) atomicAdd(out + (size_t)dv * 16 + er, ibits(v));
            }
        }
    }
}

extern "C" void kernel_launch(void* const* d_in, const int* in_sizes, int n_in,
                              void* d_out, int out_size, void* d_ws, size_t ws_size,
                              hipStream_t stream) {
    const float* x   = (const float*)d_in[0];
    const float* pos = (const float*)d_in[1];
    const int*   ei  = (const int*)d_in[2];
    const float* W1  = (const float*)d_in[3];
    const float* b1  = (const float*)d_in[4];
    const float* Wh  = (const float*)d_in[5];
    const float* bh  = (const float*)d_in[6];
    const float* Wo  = (const float*)d_in[7];
    const float* bo  = (const float*)d_in[8];
    float* out = (float*)d_out;

    zero_out_kernel<<<(out_size + 255) / 256, 256, 0, stream>>>(out, out_size);
    const int nblocks = (NTILES + 31) / 32;   // 32 tiles per 512-thread block
    edge_mfma_kernel<<<nblocks, 512, 0, stream>>>(
        x, pos, ei, W1, b1, Wh, bh, Wo, bo, out);
}

// Round 5
// 201.527 us; speedup vs baseline: 1.2483x; 1.0679x over previous
//
#include <hip/hip_runtime.h>

#define NPTS   50000
#define NEDGE  800000
#define NTILES 50000   // NEDGE/16

typedef short bf16x8 __attribute__((ext_vector_type(8)));
typedef float f32x4  __attribute__((ext_vector_type(4)));
typedef int   i32x4  __attribute__((ext_vector_type(4)));

// tanh-form GELU, |err| <= ~3e-4 vs exact erf gelu (threshold 0.171; measured absmax 0.03)
__device__ __forceinline__ float gelu_tanh(float v) {
    float v2 = v * v;
    float u2 = v * fmaf(v2, 0.0713548162726f, 1.5957691216057f);
    float e  = __expf(u2);
    float r  = __builtin_amdgcn_rcpf(e + 1.0f);
    return v - v * r;
}

// fp32 -> bf16 round-to-nearest-even (scalar path, staging only)
__device__ __forceinline__ short f2bf(float f) {
    unsigned u = __builtin_bit_cast(unsigned, f);
    unsigned r = (u + 0x7FFFu + ((u >> 16) & 1u)) >> 16;
    return (short)r;
}

// pack two f32 -> one dword of 2x bf16 (lo = a, hi = b); no builtin on gfx950
__device__ __forceinline__ int cvt_pk_bf16(float a, float b) {
    int r;
    asm("v_cvt_pk_bf16_f32 %0, %1, %2" : "=v"(r) : "v"(a), "v"(b));
    return r;
}

__device__ __forceinline__ int bperm(int addr, int v) {
    return __builtin_amdgcn_ds_bpermute(addr, v);
}
__device__ __forceinline__ int fbits(float v) { return __builtin_bit_cast(int, v); }
__device__ __forceinline__ float ibits(int v) { return __builtin_bit_cast(float, v); }

__global__ void zero_out_kernel(float* __restrict__ out, int n) {
    int i = blockIdx.x * blockDim.x + threadIdx.x;
    if (i < n) out[i] = 0.0f;
}

// Transposed-operand MFMA scheme + 2-tile software pipeline + per-pair barriers
// (barriers keep the block's 8 waves temporally clustered -> L2 residency for out/x).
__global__ __launch_bounds__(512, 4) void edge_mfma_kernel(
    const float* __restrict__ x,    // [NPTS*16]
    const float* __restrict__ pos,  // [NPTS*3]
    const int*   __restrict__ ei,   // [2*NEDGE]
    const float* __restrict__ W1,   // [6*64]
    const float* __restrict__ b1,   // [64]
    const float* __restrict__ Wh,   // [64*64]
    const float* __restrict__ bh,   // [64]
    const float* __restrict__ Wo,   // [64*256]
    const float* __restrict__ bo,   // [256]
    float* __restrict__ out)        // [NPTS*16]
{
    // A-fragment-ordered weight stores: frag[slot][lane] = bf16x8, read at base+lane*16+imm.
    __shared__ bf16x8 WoF[32][64];  // 32 KB : slot = i*2+kt
    __shared__ bf16x8 WhF[8][64];   //  8 KB : slot = m*2+kt
    __shared__ bf16x8 W1F[4][64];   //  4 KB : slot = m (K zero-pad 6->32; k==6 holds b1)
    __shared__ bf16x8 BOF[64];      //  1 KB : bo as A-frag
    __shared__ float  bhs[64];      // 256 B

    const int tid = threadIdx.x;

    // ---------------- stage weight fragments (once per block) ----------------
#pragma unroll
    for (int p = 0; p < 4; ++p) {
        int e_id = p * 512 + tid;            // 0..2047
        int s  = e_id >> 6;                  // slot 0..31
        int l  = e_id & 63;
        int er_ = l & 15, g = l >> 4;
        int i  = s >> 1, kt = s & 1;
        int n  = i * 16 + er_;
        int kb = kt * 32 + g * 8;
        bf16x8 f;
#pragma unroll
        for (int j = 0; j < 8; ++j)
            f[j] = f2bf(Wo[(kb + j) * 256 + n]);
        WoF[s][l] = f;
    }
    {
        int s  = tid >> 6;                   // 0..7
        int l  = tid & 63;
        int er_ = l & 15, g = l >> 4;
        int m  = s >> 1, kt = s & 1;
        int n  = m * 16 + er_;
        int kb = kt * 32 + g * 8;
        bf16x8 f;
#pragma unroll
        for (int j = 0; j < 8; ++j)
            f[j] = f2bf(Wh[(kb + j) * 64 + n]);
        WhF[s][l] = f;
    }
    if (tid < 256) {
        int m  = tid >> 6;
        int l  = tid & 63;
        int er_ = l & 15, g = l >> 4;
        int n  = m * 16 + er_;
        bf16x8 f;
#pragma unroll
        for (int j = 0; j < 8; ++j) {
            int k = g * 8 + j;
            float v = (k < 6) ? W1[k * 64 + n] : (k == 6 ? b1[n] : 0.0f);
            f[j] = f2bf(v);
        }
        W1F[m][l] = f;
    }
    if (tid < 64) {
        int er_ = tid & 15, g = tid >> 4;
        bf16x8 f;
#pragma unroll
        for (int j = 0; j < 8; ++j) {
            int i = g * 8 + j;
            f[j] = (g < 2) ? f2bf(bo[i * 16 + er_]) : (short)0;
        }
        BOF[tid] = f;
        bhs[tid] = bh[tid];
    }
    __syncthreads();

    const int wave = tid >> 6;
    const int lane = tid & 63;
    const int grp  = lane >> 4;   // 0..3
    const int er   = lane & 15;

    // bpermute addresses (bytes), all loop-invariant
    const int addrH0 = (er + (grp & 1) * 32) * 4;    // B-frag build, h=0
    const int addrH1 = addrH0 + 64;                  // h=1
    const bool selHi = (grp >= 2);
    int addrT[4], addrD[4];                          // msg transpose / dst gather
#pragma unroll
    for (int r = 0; r < 4; ++r) {
        addrT[r] = ((er >> 2) * 16 + grp * 4 + r) * 4;
        addrD[r] = (grp * 4 + r) * 4;
    }
    const int selT = er & 3;

    const bf16x8* wof = &WoF[0][lane];
    const bf16x8* whf = &WhF[0][lane];
    const bf16x8* w1f = &W1F[0][lane];
    const bf16x8  bofr = BOF[lane];
    const f32x4 zero = {0.f, 0.f, 0.f, 0.f};

    const int tbase = blockIdx.x * 32 + wave * 4;

    // ---- prologue: hoist ei/pos loads + ape-frag build for all 4 tiles ----
    bf16x8 apeT[4];
    int sT[4], dT[4];
#pragma unroll
    for (int tt = 0; tt < 4; ++tt) {
        int gt = tbase + tt; if (gt >= NTILES) gt = NTILES - 1;  // clamp loads; atomics guarded below
        int eb = gt << 4;
        int s = ei[eb + er];
        int d = ei[NEDGE + eb + er];
        s = min(max(s, 0), NPTS - 1);
        d = min(max(d, 0), NPTS - 1);
        sT[tt] = s; dT[tt] = d;
        float p0 = pos[s * 3 + 0], p1 = pos[s * 3 + 1], p2 = pos[s * 3 + 2];
        float p3 = pos[d * 3 + 0], p4 = pos[d * 3 + 1], p5 = pos[d * 3 + 2];
        const bool g0 = (grp == 0);
        bf16x8 ap;
        ap[0] = g0 ? f2bf(p0) : (short)0;
        ap[1] = g0 ? f2bf(p1) : (short)0;
        ap[2] = g0 ? f2bf(p2) : (short)0;
        ap[3] = g0 ? f2bf(p3) : (short)0;
        ap[4] = g0 ? f2bf(p4) : (short)0;
        ap[5] = g0 ? f2bf(p5) : (short)0;
        ap[6] = g0 ? (short)0x3F80 : (short)0;   // bf16(1.0) picks up b1 (k==6 slot)
        ap[7] = 0;
        apeT[tt] = ap;
    }

    // ---- main: 2 pairs, each pair = 2 tiles pipelined stage-by-stage ----
#pragma unroll
    for (int pp = 0; pp < 2; ++pp) {
        // temporal re-clustering: keep all 8 waves' gather/atomic bursts overlapped
        __syncthreads();

        const int t0 = 2 * pp;

        // x[src] loads for both tiles (issued early; consumed at einsum)
        float xr[2][16];
#pragma unroll
        for (int q = 0; q < 2; ++q) {
            const float4* xp = reinterpret_cast<const float4*>(x + (size_t)sT[t0 + q] * 16);
            float4 a = xp[0], b = xp[1], c = xp[2], dd = xp[3];
            xr[q][0]=a.x;  xr[q][1]=a.y;  xr[q][2]=a.z;  xr[q][3]=a.w;
            xr[q][4]=b.x;  xr[q][5]=b.y;  xr[q][6]=b.z;  xr[q][7]=b.w;
            xr[q][8]=c.x;  xr[q][9]=c.y;  xr[q][10]=c.z; xr[q][11]=c.w;
            xr[q][12]=dd.x; xr[q][13]=dd.y; xr[q][14]=dd.z; xr[q][15]=dd.w;
        }

        // ---- layer 1: H1^T = W1F @ PE^T, gelu (bias folded into K) ----
        float g1[2][4][4];
#pragma unroll
        for (int q = 0; q < 2; ++q)
#pragma unroll
            for (int m = 0; m < 4; ++m) {
                f32x4 c = __builtin_amdgcn_mfma_f32_16x16x32_bf16(w1f[m * 64], apeT[t0 + q], zero, 0, 0, 0);
#pragma unroll
                for (int r = 0; r < 4; ++r) g1[q][m][r] = gelu_tanh(c[r]);
            }

        // ---- build B2 frags: pack-then-permute (2 elems per ds_bpermute) ----
        // dword d=h*2+rp of kt-frag = bperm(addr_h, pk(g[2kt+mi][2rp], g[2kt+mi][2rp+1])), mi sel by grp
        bf16x8 B2[2][2];
#pragma unroll
        for (int q = 0; q < 2; ++q)
#pragma unroll
            for (int kt = 0; kt < 2; ++kt) {
                int pk0[2], pk1[2];
#pragma unroll
                for (int rp = 0; rp < 2; ++rp) {
                    pk0[rp] = cvt_pk_bf16(g1[q][2 * kt + 0][2 * rp], g1[q][2 * kt + 0][2 * rp + 1]);
                    pk1[rp] = cvt_pk_bf16(g1[q][2 * kt + 1][2 * rp], g1[q][2 * kt + 1][2 * rp + 1]);
                }
                i32x4 w;
#pragma unroll
                for (int h = 0; h < 2; ++h) {
                    int ah = h ? addrH1 : addrH0;
#pragma unroll
                    for (int rp = 0; rp < 2; ++rp) {
                        int vA = bperm(ah, pk0[rp]);
                        int vB = bperm(ah, pk1[rp]);
                        w[h * 2 + rp] = selHi ? vB : vA;
                    }
                }
                B2[q][kt] = __builtin_bit_cast(bf16x8, w);
            }

        // ---- layer 2: H2^T = WhF @ H1^T + bh, gelu ----
        float g2[2][4][4];
#pragma unroll
        for (int q = 0; q < 2; ++q)
#pragma unroll
            for (int m = 0; m < 4; ++m) {
                f32x4 c = __builtin_amdgcn_mfma_f32_16x16x32_bf16(whf[(2 * m + 0) * 64], B2[q][0], zero, 0, 0, 0);
                c = __builtin_amdgcn_mfma_f32_16x16x32_bf16(whf[(2 * m + 1) * 64], B2[q][1], c, 0, 0, 0);
                float4 b4 = *reinterpret_cast<const float4*>(&bhs[m * 16 + grp * 4]);
                float bb[4] = {b4.x, b4.y, b4.z, b4.w};
#pragma unroll
                for (int r = 0; r < 4; ++r) g2[q][m][r] = gelu_tanh(c[r] + bb[r]);
            }

        // ---- build B3 frags (same pack-then-permute) ----
        bf16x8 B3[2][2];
#pragma unroll
        for (int q = 0; q < 2; ++q)
#pragma unroll
            for (int kt = 0; kt < 2; ++kt) {
                int pk0[2], pk1[2];
#pragma unroll
                for (int rp = 0; rp < 2; ++rp) {
                    pk0[rp] = cvt_pk_bf16(g2[q][2 * kt + 0][2 * rp], g2[q][2 * kt + 0][2 * rp + 1]);
                    pk1[rp] = cvt_pk_bf16(g2[q][2 * kt + 1][2 * rp], g2[q][2 * kt + 1][2 * rp + 1]);
                }
                i32x4 w;
#pragma unroll
                for (int h = 0; h < 2; ++h) {
                    int ah = h ? addrH1 : addrH0;
#pragma unroll
                    for (int rp = 0; rp < 2; ++rp) {
                        int vA = bperm(ah, pk0[rp]);
                        int vB = bperm(ah, pk1[rp]);
                        w[h * 2 + rp] = selHi ? vB : vA;
                    }
                }
                B3[q][kt] = __builtin_bit_cast(bf16x8, w);
            }

        // ---- bo contribution: msg = BOF @ X^T (K zero-padded 16->32) ----
        f32x4 msg[2];
#pragma unroll
        for (int q = 0; q < 2; ++q) {
            bf16x8 xb;
#pragma unroll
            for (int j = 0; j < 8; ++j) {
                float v = (grp == 0) ? xr[q][j] : ((grp == 1) ? xr[q][j + 8] : 0.0f);
                xb[j] = (grp < 2) ? f2bf(v) : (short)0;
            }
            msg[q] = __builtin_amdgcn_mfma_f32_16x16x32_bf16(bofr, xb, zero, 0, 0, 0);
        }

        // ---- layer 3 + einsum, q-interleaved for MFMA ILP ----
#pragma unroll
        for (int i = 0; i < 16; ++i)
#pragma unroll
            for (int q = 0; q < 2; ++q) {
                f32x4 c = __builtin_amdgcn_mfma_f32_16x16x32_bf16(wof[(2 * i + 0) * 64], B3[q][0], zero, 0, 0, 0);
                c = __builtin_amdgcn_mfma_f32_16x16x32_bf16(wof[(2 * i + 1) * 64], B3[q][1], c, 0, 0, 0);
#pragma unroll
                for (int r = 0; r < 4; ++r)
                    msg[q][r] = fmaf(xr[q][i], c[r], msg[q][r]);
            }

        // ---- transpose msg across lanes -> line-packed atomics (one full 64B line/edge) ----
#pragma unroll
        for (int q = 0; q < 2; ++q) {
            const int gt = tbase + t0 + q;
            const bool ok = (gt < NTILES);
#pragma unroll
            for (int rd = 0; rd < 4; ++rd) {
                int u0 = bperm(addrT[rd], fbits(msg[q][0]));
                int u1 = bperm(addrT[rd], fbits(msg[q][1]));
                int u2 = bperm(addrT[rd], fbits(msg[q][2]));
                int u3 = bperm(addrT[rd], fbits(msg[q][3]));
                int v  = (selT == 0) ? u0 : (selT == 1) ? u1 : (selT == 2) ? u2 : u3;
                int dv = bperm(addrD[rd], dT[t0 + q]);
                if (ok) atomicAdd(out + (size_t)dv * 16 + er, ibits(v));
            }
        }
    }
}

extern "C" void kernel_launch(void* const* d_in, const int* in_sizes, int n_in,
                              void* d_out, int out_size, void* d_ws, size_t ws_size,
                              hipStream_t stream) {
    const float* x   = (const float*)d_in[0];
    const float* pos = (const float*)d_in[1];
    const int*   ei  = (const int*)d_in[2];
    const float* W1  = (const float*)d_in[3];
    const float* b1  = (const float*)d_in[4];
    const float* Wh  = (const float*)d_in[5];
    const float* bh  = (const float*)d_in[6];
    const float* Wo  = (const float*)d_in[7];
    const float* bo  = (const float*)d_in[8];
    float* out = (float*)d_out;

    zero_out_kernel<<<(out_size + 255) / 256, 256, 0, stream>>>(out, out_size);
    const int nblocks = (NTILES + 31) / 32;   // 32 tiles per 512-thread block
    edge_mfma_kernel<<<nblocks, 512, 0, stream>>>(
        x, pos, ei, W1, b1, Wh, bh, Wo, bo, out);
}